// Round 1
// baseline (131.000 us; speedup 1.0000x reference)
//
#include <hip/hip_runtime.h>
#include <hip/hip_bf16.h>
#include <math.h>

// Problem constants
#define BATCH 8
#define HH 512
#define WW 512
#define COUT 256
#define NPTS 11          // 5 + 6
#define CASC 3
#define FH 128           // conv output spatial
#define FW 128
#define KT 49            // 7x7 taps
#define NBK (BATCH*NPTS) // 88

// ws layout (floats)
#define FOLD_OFF   0          // 850 floats: scoreW[11][49], scoreB[11], shiftW[6][49], shiftB[6]
#define SCORES_OFF 1024       // 8*11*128*128 = 1441792 floats
#define PVAL_OFF   (1024 + 1441792)         // 352 floats
#define PIDX_OFF   (PVAL_OFF + 352)         // 352 ints

#define STEPC (127.0f/511.0f)

// ---------------------------------------------------------------------------
// Kernel 1: fold weights.
// 850 outputs = 17 rows x 50 cols (col 49 = bias term).
// rows 0..10  -> score_w[k][t] = sum_c fc_w[k,c] * (bw[c,0,t]+bw[c,1,t]+bw[c,2,t])
// rows 11..16 -> shift_w[i][j][t] = sum_c head_w[i,c,j] * w_eff[c,t]
// t==49: bias = sum_c coef*backbone_b[c] + (fc_b | head_b)
// One wave (64 threads) per output, lanes split the c-sum.
__global__ __launch_bounds__(64) void fold_kernel(
    const float* __restrict__ bw, const float* __restrict__ bb,
    const float* __restrict__ fcw, const float* __restrict__ fcb,
    const float* __restrict__ hw, const float* __restrict__ hb,
    float* __restrict__ fold) {
  int id = blockIdx.x;          // 0..849
  int row = id / 50, t = id % 50;
  int lane = threadIdx.x;       // 0..63
  float acc = 0.f;
  for (int c = lane; c < COUT; c += 64) {
    float coef;
    if (row < NPTS) {
      coef = fcw[row*COUT + c];
    } else {
      int r = row - NPTS;
      coef = hw[(r >> 1)*(COUT*2) + c*2 + (r & 1)];
    }
    float wsum;
    if (t < KT) {
      const float* p = bw + c*(3*KT) + t;
      wsum = p[0] + p[KT] + p[2*KT];
    } else {
      wsum = bb[c];
    }
    acc += coef * wsum;
  }
  #pragma unroll
  for (int off = 32; off > 0; off >>= 1) acc += __shfl_down(acc, off);
  if (lane == 0) {
    if (t == KT) acc += (row < NPTS) ? fcb[row] : hb[row - NPTS];
    if (row < NPTS) {
      if (t < KT) fold[row*KT + t] = acc;
      else        fold[NPTS*KT + row] = acc;                  // scoreB at 539..549
    } else {
      int r = row - NPTS;
      if (t < KT) fold[550 + r*KT + t] = acc;                 // shiftW
      else        fold[844 + r] = acc;                        // shiftB
    }
  }
}

// ---------------------------------------------------------------------------
// Kernel 2: scores (8,11,128,128) via folded 7x7 stride-4 conv on (img-0.5).
__global__ __launch_bounds__(256) void scores_kernel(
    const float* __restrict__ img, const float* __restrict__ fold,
    float* __restrict__ scores) {
  __shared__ float w[550];
  for (int i = threadIdx.x; i < 550; i += 256) w[i] = fold[i];
  __syncthreads();
  int g = blockIdx.x*256 + threadIdx.x;     // 0..131071
  int b = g >> 14;
  int rem = g & 16383;
  int y = rem >> 7, x = rem & 127;
  const float* im = img + (size_t)b * (HH*WW);
  float acc[NPTS];
  #pragma unroll
  for (int k = 0; k < NPTS; ++k) acc[k] = w[NPTS*KT + k];
  int iy0 = y*4 - 3, ix0 = x*4 - 3;
  #pragma unroll
  for (int kh = 0; kh < 7; ++kh) {
    int iy = iy0 + kh;
    if (iy < 0 || iy >= HH) continue;
    #pragma unroll
    for (int kw = 0; kw < 7; ++kw) {
      int ix = ix0 + kw;
      if (ix < 0 || ix >= WW) continue;
      float xv = im[iy*WW + ix] - 0.5f;
      int t = kh*7 + kw;
      #pragma unroll
      for (int k = 0; k < NPTS; ++k) acc[k] = fmaf(w[k*KT + t], xv, acc[k]);
    }
  }
  float* out = scores + (size_t)b * (NPTS*FH*FW) + rem;
  #pragma unroll
  for (int k = 0; k < NPTS; ++k) out[(size_t)k*(FH*FW)] = acc[k];
}

// ---------------------------------------------------------------------------
// Kernel 3: argmax over 512x512 bilinear(align_corners) upsample of each
// (b,k) score map. Grid = 88*4 blocks: block q handles oy in [q*128, q*128+128).
// Exact reference formula: v = (s[y0][x0]*(1-wy)+s[y1][x0]*wy)*(1-wx)
//                            + (s[y0][x1]*(1-wy)+s[y1][x1]*wy)*wx
// Lanes spread over ox (banks spread over x). Row subrange staged in LDS.
__global__ __launch_bounds__(256) void argmax_kernel(
    const float* __restrict__ scores, float* __restrict__ pval,
    int* __restrict__ pidx) {
  __shared__ float s[34*128];
  __shared__ float rv[256];
  __shared__ int   ri[256];
  int bk = blockIdx.x >> 2;
  int q  = blockIdx.x & 3;
  const float* src = scores + (size_t)bk * (FH*FW);

  int oyb = q*128;
  int ybase = (int)((float)oyb * STEPC);
  int ylast = (int)((float)(oyb + 127) * STEPC);
  int yend  = min(ylast + 1, FH - 1);
  int rows  = yend - ybase + 1;              // <= 34
  for (int i = threadIdx.x; i < rows*FW; i += 256) s[i] = src[ybase*FW + i];
  __syncthreads();

  // per-thread x columns (constant over oy)
  int ox0 = threadIdx.x*2, ox1 = ox0 + 1;
  float tx0 = (float)ox0 * STEPC, tx1 = (float)ox1 * STEPC;
  int xa0 = (int)tx0, xb0 = (int)tx1;
  float wx0 = tx0 - (float)xa0, wx1 = tx1 - (float)xb0;
  int xa1 = min(xa0 + 1, FW - 1), xb1 = min(xb0 + 1, FW - 1);
  float omwx0 = 1.f - wx0, omwx1 = 1.f - wx1;

  float best = -3.4028235e38f;
  int bidx = 0x7fffffff;
  for (int j = 0; j < 128; ++j) {
    int oy = oyb + j;
    float ty = (float)oy * STEPC;
    int y0 = (int)ty;
    float wy = ty - (float)y0;
    float omwy = 1.f - wy;
    int y1 = min(y0 + 1, FH - 1);
    const float* r0 = s + (y0 - ybase)*FW;
    const float* r1 = s + (y1 - ybase)*FW;
    {
      float a = r0[xa0], bb_ = r1[xa0], c = r0[xa1], d = r1[xa1];
      float top0 = a*omwy + bb_*wy;
      float top1 = c*omwy + d*wy;
      float v = top0*omwx0 + top1*wx0;
      if (v > best) { best = v; bidx = oy*512 + ox0; }
    }
    {
      float a = r0[xb0], bb_ = r1[xb0], c = r0[xb1], d = r1[xb1];
      float top0 = a*omwy + bb_*wy;
      float top1 = c*omwy + d*wy;
      float v = top0*omwx1 + top1*wx1;
      if (v > best) { best = v; bidx = oy*512 + ox1; }
    }
  }
  __syncthreads();
  rv[threadIdx.x] = best; ri[threadIdx.x] = bidx;
  __syncthreads();
  for (int off = 128; off > 0; off >>= 1) {
    if ((int)threadIdx.x < off) {
      float ov = rv[threadIdx.x + off]; int oi = ri[threadIdx.x + off];
      float mv = rv[threadIdx.x];       int mi = ri[threadIdx.x];
      if (ov > mv || (ov == mv && oi < mi)) { rv[threadIdx.x] = ov; ri[threadIdx.x] = oi; }
    }
    __syncthreads();
  }
  if (threadIdx.x == 0) {
    pval[bk*4 + q] = rv[0];
    pidx[bk*4 + q] = ri[0];
  }
}

// ---------------------------------------------------------------------------
// Kernel 4: merge partials -> coords, then 3 cascade refinements with folded
// shift weights (direct conv at the gathered point), write final coords.
__global__ __launch_bounds__(128) void cascade_kernel(
    const float* __restrict__ img, const float* __restrict__ fold,
    const float* __restrict__ pval, const int* __restrict__ pidx,
    float* __restrict__ out) {
  int p = threadIdx.x;    // bk index = b*11 + k
  if (p >= NBK) return;
  float best = pval[p*4]; int bidx = pidx[p*4];
  #pragma unroll
  for (int q = 1; q < 4; ++q) {
    float v = pval[p*4 + q]; int i = pidx[p*4 + q];
    if (v > best || (v == best && i < bidx)) { best = v; bidx = i; }
  }
  float cx = (float)(bidx & 511);
  float cy = (float)(bidx >> 9);
  int b = p / NPTS;
  const float* im = img + (size_t)b * (HH*WW);
  for (int i = 0; i < CASC; ++i) {
    // hi from y-coord, wi from x-coord; jnp.round = RNE = rintf
    float ry = rintf(cy * 0.25f), rx = rintf(cx * 0.25f);
    int hi = (int)fminf(fmaxf(ry, 0.f), (float)(FH - 1));
    int wi = (int)fminf(fmaxf(rx, 0.f), (float)(FW - 1));
    float s0 = fold[844 + i*2 + 0];
    float s1 = fold[844 + i*2 + 1];
    int iy0 = hi*4 - 3, ix0 = wi*4 - 3;
    for (int kh = 0; kh < 7; ++kh) {
      int iy = iy0 + kh;
      if (iy < 0 || iy >= HH) continue;
      for (int kw = 0; kw < 7; ++kw) {
        int ix = ix0 + kw;
        if (ix < 0 || ix >= WW) continue;
        float xv = im[iy*WW + ix] - 0.5f;
        int t = kh*7 + kw;
        s0 = fmaf(fold[550 + (i*2 + 0)*KT + t], xv, s0);
        s1 = fmaf(fold[550 + (i*2 + 1)*KT + t], xv, s1);
      }
    }
    cx += s0;
    cy += s1;
  }
  out[p*2 + 0] = cx;
  out[p*2 + 1] = cy;
}

// ---------------------------------------------------------------------------
extern "C" void kernel_launch(void* const* d_in, const int* in_sizes, int n_in,
                              void* d_out, int out_size, void* d_ws, size_t ws_size,
                              hipStream_t stream) {
  const float* img = (const float*)d_in[0];   // (8,1,512,512)
  const float* bw  = (const float*)d_in[1];   // (256,3,7,7)
  const float* bb  = (const float*)d_in[2];   // (256,)
  const float* fcw = (const float*)d_in[3];   // (11,256)
  const float* fcb = (const float*)d_in[4];   // (11,)
  const float* hw  = (const float*)d_in[5];   // (3,256,2)
  const float* hb  = (const float*)d_in[6];   // (3,2)
  float* out = (float*)d_out;                 // (8,11,2) f32

  float* ws     = (float*)d_ws;
  float* fold   = ws + FOLD_OFF;
  float* scores = ws + SCORES_OFF;
  float* pval   = ws + PVAL_OFF;
  int*   pidx   = (int*)(ws + PIDX_OFF);

  fold_kernel<<<850, 64, 0, stream>>>(bw, bb, fcw, fcb, hw, hb, fold);
  scores_kernel<<<512, 256, 0, stream>>>(img, fold, scores);
  argmax_kernel<<<NBK*4, 256, 0, stream>>>(scores, pval, pidx);
  cascade_kernel<<<1, 128, 0, stream>>>(img, fold, pval, pidx, out);
}

// Round 2
// 123.868 us; speedup vs baseline: 1.0576x; 1.0576x over previous
//
#include <hip/hip_runtime.h>
#include <hip/hip_bf16.h>
#include <math.h>

// Problem constants
#define BATCH 8
#define HH 512
#define WW 512
#define COUT 256
#define NPTS 11          // 5 + 6
#define CASC 3
#define FH 128           // conv output spatial
#define FW 128
#define KT 49            // 7x7 taps
#define NBK (BATCH*NPTS) // 88
#define NSPLIT 8         // argmax row-splits per (b,k) map
#define OROWS (HH/NSPLIT) // 64 output rows per split

// ws layout (floats)
#define FOLD_OFF   0          // 850 floats: scoreW[11][49], scoreB[11], shiftW[6][49], shiftB[6]
#define SCORES_OFF 1024       // 8*11*128*128 = 1441792 floats
#define PVAL_OFF   (1024 + 1441792)         // 704 floats
#define PIDX_OFF   (PVAL_OFF + 704)         // 704 ints

#define STEPC (127.0f/511.0f)

// ---------------------------------------------------------------------------
// Kernel 1: fold weights (unchanged from R1 — ~3 us, not the bottleneck).
// 850 outputs = 17 rows x 50 cols (col 49 = bias term).
__global__ __launch_bounds__(64) void fold_kernel(
    const float* __restrict__ bw, const float* __restrict__ bb,
    const float* __restrict__ fcw, const float* __restrict__ fcb,
    const float* __restrict__ hw, const float* __restrict__ hb,
    float* __restrict__ fold) {
  int id = blockIdx.x;          // 0..849
  int row = id / 50, t = id % 50;
  int lane = threadIdx.x;       // 0..63
  float acc = 0.f;
  for (int c = lane; c < COUT; c += 64) {
    float coef;
    if (row < NPTS) {
      coef = fcw[row*COUT + c];
    } else {
      int r = row - NPTS;
      coef = hw[(r >> 1)*(COUT*2) + c*2 + (r & 1)];
    }
    float wsum;
    if (t < KT) {
      const float* p = bw + c*(3*KT) + t;
      wsum = p[0] + p[KT] + p[2*KT];
    } else {
      wsum = bb[c];
    }
    acc += coef * wsum;
  }
  #pragma unroll
  for (int off = 32; off > 0; off >>= 1) acc += __shfl_down(acc, off);
  if (lane == 0) {
    if (t == KT) acc += (row < NPTS) ? fcb[row] : hb[row - NPTS];
    if (row < NPTS) {
      if (t < KT) fold[row*KT + t] = acc;
      else        fold[NPTS*KT + row] = acc;                  // scoreB at 539..549
    } else {
      int r = row - NPTS;
      if (t < KT) fold[550 + r*KT + t] = acc;                 // shiftW
      else        fold[844 + r] = acc;                        // shiftB
    }
  }
}

// ---------------------------------------------------------------------------
// Kernel 2: scores (8,11,128,128) via folded 7x7 stride-4 conv on (img-0.5).
// R2 change: weights read directly from global with loop-uniform indices ->
// compiler emits s_load through the scalar cache (broadcast, frees LDS/VMEM
// vector pipes). No LDS copy. Arithmetic order identical to R1.
__global__ __launch_bounds__(256) void scores_kernel(
    const float* __restrict__ img, const float* __restrict__ fold,
    float* __restrict__ scores) {
  int g = blockIdx.x*256 + threadIdx.x;     // 0..131071
  int b = g >> 14;
  int rem = g & 16383;
  int y = rem >> 7, x = rem & 127;
  const float* im = img + (size_t)b * (HH*WW);
  float acc[NPTS];
  #pragma unroll
  for (int k = 0; k < NPTS; ++k) acc[k] = fold[NPTS*KT + k];   // uniform -> s_load
  int iy0 = y*4 - 3, ix0 = x*4 - 3;
  #pragma unroll
  for (int kh = 0; kh < 7; ++kh) {
    int iy = iy0 + kh;
    if (iy < 0 || iy >= HH) continue;
    #pragma unroll
    for (int kw = 0; kw < 7; ++kw) {
      int ix = ix0 + kw;
      if (ix < 0 || ix >= WW) continue;
      float xv = im[iy*WW + ix] - 0.5f;
      int t = kh*7 + kw;
      #pragma unroll
      for (int k = 0; k < NPTS; ++k) acc[k] = fmaf(fold[k*KT + t], xv, acc[k]);
    }
  }
  float* out = scores + (size_t)b * (NPTS*FH*FW) + rem;
  #pragma unroll
  for (int k = 0; k < NPTS; ++k) out[(size_t)k*(FH*FW)] = acc[k];
}

// ---------------------------------------------------------------------------
// Kernel 3: argmax over 512x512 bilinear(align_corners) upsample of each
// (b,k) score map. Grid = 88*NSPLIT blocks; block q handles oy in
// [q*OROWS, q*OROWS+OROWS). R2 changes: (a) 8-way split (shorter serial
// scan, 2.75 blocks/CU), (b) corner values cached in registers and reloaded
// from LDS only when y0 changes (wave-uniform branch, ~every 4th iter).
// Per-point arithmetic is bit-identical to R1 (which scored absmax 0.0).
__global__ __launch_bounds__(256) void argmax_kernel(
    const float* __restrict__ scores, float* __restrict__ pval,
    int* __restrict__ pidx) {
  __shared__ float s[20*128];
  __shared__ float rv[256];
  __shared__ int   ri[256];
  int bk = blockIdx.x / NSPLIT;
  int q  = blockIdx.x % NSPLIT;
  const float* src = scores + (size_t)bk * (FH*FW);

  int oyb = q*OROWS;
  int ybase = (int)((float)oyb * STEPC);
  int ylast = (int)((float)(oyb + OROWS - 1) * STEPC);
  int yend  = min(ylast + 1, FH - 1);
  int rows  = yend - ybase + 1;              // <= 18
  for (int i = threadIdx.x; i < rows*FW; i += 256) s[i] = src[ybase*FW + i];
  __syncthreads();

  // per-thread x columns (constant over oy)
  int ox0 = threadIdx.x*2, ox1 = ox0 + 1;
  float tx0 = (float)ox0 * STEPC, tx1 = (float)ox1 * STEPC;
  int xa0 = (int)tx0, xb0 = (int)tx1;
  float wx0 = tx0 - (float)xa0, wx1 = tx1 - (float)xb0;
  int xa1 = min(xa0 + 1, FW - 1), xb1 = min(xb0 + 1, FW - 1);
  float omwx0 = 1.f - wx0, omwx1 = 1.f - wx1;

  float best = -3.4028235e38f;
  int bidx = 0x7fffffff;
  int prevY0 = -1;
  float a0=0.f, b0=0.f, c0=0.f, d0=0.f;   // point 0 corners
  float a1=0.f, b1=0.f, c1=0.f, d1=0.f;   // point 1 corners
  for (int j = 0; j < OROWS; ++j) {
    int oy = oyb + j;
    float ty = (float)oy * STEPC;
    int y0 = (int)ty;
    float wy = ty - (float)y0;
    float omwy = 1.f - wy;
    if (y0 != prevY0) {                    // wave-uniform branch
      int y1 = min(y0 + 1, FH - 1);
      const float* r0 = s + (y0 - ybase)*FW;
      const float* r1 = s + (y1 - ybase)*FW;
      a0 = r0[xa0]; b0 = r1[xa0]; c0 = r0[xa1]; d0 = r1[xa1];
      a1 = r0[xb0]; b1 = r1[xb0]; c1 = r0[xb1]; d1 = r1[xb1];
      prevY0 = y0;
    }
    {
      float top0 = a0*omwy + b0*wy;
      float top1 = c0*omwy + d0*wy;
      float v = top0*omwx0 + top1*wx0;
      if (v > best) { best = v; bidx = oy*512 + ox0; }
    }
    {
      float top0 = a1*omwy + b1*wy;
      float top1 = c1*omwy + d1*wy;
      float v = top0*omwx1 + top1*wx1;
      if (v > best) { best = v; bidx = oy*512 + ox1; }
    }
  }
  __syncthreads();
  rv[threadIdx.x] = best; ri[threadIdx.x] = bidx;
  __syncthreads();
  for (int off = 128; off > 0; off >>= 1) {
    if ((int)threadIdx.x < off) {
      float ov = rv[threadIdx.x + off]; int oi = ri[threadIdx.x + off];
      float mv = rv[threadIdx.x];       int mi = ri[threadIdx.x];
      if (ov > mv || (ov == mv && oi < mi)) { rv[threadIdx.x] = ov; ri[threadIdx.x] = oi; }
    }
    __syncthreads();
  }
  if (threadIdx.x == 0) {
    pval[bk*NSPLIT + q] = rv[0];
    pidx[bk*NSPLIT + q] = ri[0];
  }
}

// ---------------------------------------------------------------------------
// Kernel 4: merge partials -> coords, then 3 cascade refinements with folded
// shift weights (direct conv at the gathered point), write final coords.
__global__ __launch_bounds__(128) void cascade_kernel(
    const float* __restrict__ img, const float* __restrict__ fold,
    const float* __restrict__ pval, const int* __restrict__ pidx,
    float* __restrict__ out) {
  int p = threadIdx.x;    // bk index = b*11 + k
  if (p >= NBK) return;
  float best = pval[p*NSPLIT]; int bidx = pidx[p*NSPLIT];
  #pragma unroll
  for (int q = 1; q < NSPLIT; ++q) {
    float v = pval[p*NSPLIT + q]; int i = pidx[p*NSPLIT + q];
    if (v > best || (v == best && i < bidx)) { best = v; bidx = i; }
  }
  float cx = (float)(bidx & 511);
  float cy = (float)(bidx >> 9);
  int b = p / NPTS;
  const float* im = img + (size_t)b * (HH*WW);
  for (int i = 0; i < CASC; ++i) {
    // hi from y-coord, wi from x-coord; jnp.round = RNE = rintf
    float ry = rintf(cy * 0.25f), rx = rintf(cx * 0.25f);
    int hi = (int)fminf(fmaxf(ry, 0.f), (float)(FH - 1));
    int wi = (int)fminf(fmaxf(rx, 0.f), (float)(FW - 1));
    float s0 = fold[844 + i*2 + 0];
    float s1 = fold[844 + i*2 + 1];
    int iy0 = hi*4 - 3, ix0 = wi*4 - 3;
    for (int kh = 0; kh < 7; ++kh) {
      int iy = iy0 + kh;
      if (iy < 0 || iy >= HH) continue;
      for (int kw = 0; kw < 7; ++kw) {
        int ix = ix0 + kw;
        if (ix < 0 || ix >= WW) continue;
        float xv = im[iy*WW + ix] - 0.5f;
        int t = kh*7 + kw;
        s0 = fmaf(fold[550 + (i*2 + 0)*KT + t], xv, s0);
        s1 = fmaf(fold[550 + (i*2 + 1)*KT + t], xv, s1);
      }
    }
    cx += s0;
    cy += s1;
  }
  out[p*2 + 0] = cx;
  out[p*2 + 1] = cy;
}

// ---------------------------------------------------------------------------
extern "C" void kernel_launch(void* const* d_in, const int* in_sizes, int n_in,
                              void* d_out, int out_size, void* d_ws, size_t ws_size,
                              hipStream_t stream) {
  const float* img = (const float*)d_in[0];   // (8,1,512,512)
  const float* bw  = (const float*)d_in[1];   // (256,3,7,7)
  const float* bb  = (const float*)d_in[2];   // (256,)
  const float* fcw = (const float*)d_in[3];   // (11,256)
  const float* fcb = (const float*)d_in[4];   // (11,)
  const float* hw  = (const float*)d_in[5];   // (3,256,2)
  const float* hb  = (const float*)d_in[6];   // (3,2)
  float* out = (float*)d_out;                 // (8,11,2) f32

  float* ws     = (float*)d_ws;
  float* fold   = ws + FOLD_OFF;
  float* scores = ws + SCORES_OFF;
  float* pval   = ws + PVAL_OFF;
  int*   pidx   = (int*)(ws + PIDX_OFF);

  fold_kernel<<<850, 64, 0, stream>>>(bw, bb, fcw, fcb, hw, hb, fold);
  scores_kernel<<<512, 256, 0, stream>>>(img, fold, scores);
  argmax_kernel<<<NBK*NSPLIT, 256, 0, stream>>>(scores, pval, pidx);
  cascade_kernel<<<1, 128, 0, stream>>>(img, fold, pval, pidx, out);
}